// Round 1
// 1501.510 us; speedup vs baseline: 1.2066x; 1.2066x over previous
//
#include <hip/hip_runtime.h>
#include <math.h>

#define TSEQ_MAX 256

typedef float v2f __attribute__((ext_vector_type(2)));

__device__ __forceinline__ float sigmf(float x){ return 1.f/(1.f+__expf(-x)); }
__device__ __forceinline__ float tanh_f(float x){ return 1.f - 2.f/(__expf(2.f*x)+1.f); }

// ---------------- GCN degree / norm ----------------
__global__ void k_deg_init(float* deg, int N){
    int i = blockIdx.x*256 + threadIdx.x;
    if (i < N) deg[i] = 1.0f;              // self-loop weight
}
__global__ void k_deg_acc(const int* __restrict__ ei, const float* __restrict__ ew, float* deg, int E){
    int e = blockIdx.x*256 + threadIdx.x;
    if (e < E) atomicAdd(&deg[ei[E + e]], ew[e]);
}
__global__ void k_dis(float* deg, int N){
    int i = blockIdx.x*256 + threadIdx.x;
    if (i < N){ float d = deg[i]; deg[i] = (d > 0.f) ? rsqrtf(fmaxf(d, 1e-12f)) : 0.f; }
}

// ---------------- CSR build: count, scan, scatter ----------------
__global__ void k_count(const int* __restrict__ ei, int* __restrict__ cnt, int E){
    int e = blockIdx.x*256 + threadIdx.x;
    if (e < E) atomicAdd(&cnt[ei[E + e]], 1);
}

__global__ __launch_bounds__(256) void k_scan1(const int* __restrict__ cnt, int* __restrict__ base,
        int* __restrict__ partials, int N){
    __shared__ int sh[256];
    int tid = threadIdx.x;
    int i0 = blockIdx.x*1024 + tid*4;
    int v0=0,v1=0,v2=0,v3=0;
    if (i0+0 < N) v0 = cnt[i0+0];
    if (i0+1 < N) v1 = cnt[i0+1];
    if (i0+2 < N) v2 = cnt[i0+2];
    if (i0+3 < N) v3 = cnt[i0+3];
    int tsum = v0+v1+v2+v3;
    sh[tid] = tsum;
    __syncthreads();
    for (int off = 1; off < 256; off <<= 1){
        int val = (tid >= off) ? sh[tid-off] : 0;
        __syncthreads();
        sh[tid] += val;
        __syncthreads();
    }
    int excl = sh[tid] - tsum;
    if (i0+0 < N) base[i0+0] = excl;
    if (i0+1 < N) base[i0+1] = excl + v0;
    if (i0+2 < N) base[i0+2] = excl + v0 + v1;
    if (i0+3 < N) base[i0+3] = excl + v0 + v1 + v2;
    if (tid == 255) partials[blockIdx.x] = sh[255];
}
__global__ __launch_bounds__(128) void k_scan2(int* partials, int nb){
    __shared__ int sh[128];
    int tid = threadIdx.x;
    int v = (tid < nb) ? partials[tid] : 0;
    sh[tid] = v;
    __syncthreads();
    for (int off = 1; off < 128; off <<= 1){
        int val = (tid >= off) ? sh[tid-off] : 0;
        __syncthreads();
        sh[tid] += val;
        __syncthreads();
    }
    if (tid < nb) partials[tid] = sh[tid] - v;   // exclusive
}
__global__ void k_scan3(int* base, int* cursor, const int* __restrict__ partials, int N, int E){
    int i = blockIdx.x*256 + threadIdx.x;
    if (i < N){
        int v = base[i] + partials[i >> 10];
        base[i] = v; cursor[i] = v;
    }
    if (i == N) base[N] = E;
}
__global__ void k_scatter(const int* __restrict__ ei, const float* __restrict__ ew,
        const float* __restrict__ dis, int* cursor, int2* __restrict__ sorted, int E){
    int e = blockIdx.x*256 + threadIdx.x;
    if (e < E){
        int r = ei[e], c = ei[E + e];
        float nrm = dis[r] * ew[e] * dis[c];
        int pos = atomicAdd(&cursor[c], 1);
        sorted[pos] = make_int2(r, __float_as_int(nrm));
    }
}

// ---------------- GCN layer 1: xw1 = feats@W1 ----------------
__global__ __launch_bounds__(256) void k_xw1(const float* __restrict__ xc, const float* __restrict__ te,
        const float* __restrict__ emb, const float* __restrict__ W1,
        float* __restrict__ xw1, int N){
    __shared__ float Ws[134*64];
    __shared__ float fs[4][136];
    int tid = threadIdx.x;
    for (int i = tid; i < 134*64; i += 256) Ws[i] = W1[i];
    int sub = tid >> 6, lane = tid & 63;
    int node = blockIdx.x*4 + sub;
    if (node < N){
        fs[sub][2+lane]      = emb[node*128 + lane];
        fs[sub][2+64+lane]   = emb[node*128 + 64 + lane];
        if (lane < 2) fs[sub][lane]       = xc[node*2 + lane];
        if (lane < 4) fs[sub][130 + lane] = te[node*4 + lane];
    }
    __syncthreads();
    if (node < N){
        float acc = 0.f;
        #pragma unroll 2
        for (int k = 0; k < 134; k++) acc += fs[sub][k] * Ws[k*64 + lane];
        xw1[node*64 + lane] = acc;
    }
}

// ---------------- CSR gather, 64 channels, unroll-4 for MLP ----------------
// RELU=false: layer-1 aggregation (adds bias b).
// RELU=true : layer-2 aggregation over relu(out1) PRE-projection — uses
//             A@(relu(Z1)@W2) == (A@relu(Z1))@W2 to gather 256B/edge
//             instead of 512B/edge; bias added later in k_proj.
template<bool RELU>
__global__ __launch_bounds__(256) void k_gather64(const int2* __restrict__ sorted, const int* __restrict__ base,
        const float* __restrict__ dis, const float* __restrict__ src, const float* __restrict__ b,
        float* __restrict__ outp, int N){
    int node = blockIdx.x*4 + (threadIdx.x >> 6);
    int lane = threadIdx.x & 63;
    if (node >= N) return;
    int s = base[node], e_end = base[node+1];
    float d = dis[node];
    float self = src[(size_t)node*64 + lane];
    if (RELU) self = fmaxf(self, 0.f);
    float acc = d*d*self;
    if (!RELU) acc += b[lane];
    int e = s;
    for (; e + 4 <= e_end; e += 4){
        int2 p0 = sorted[e+0];
        int2 p1 = sorted[e+1];
        int2 p2 = sorted[e+2];
        int2 p3 = sorted[e+3];
        float v0 = src[(size_t)p0.x*64 + lane];
        float v1 = src[(size_t)p1.x*64 + lane];
        float v2 = src[(size_t)p2.x*64 + lane];
        float v3 = src[(size_t)p3.x*64 + lane];
        if (RELU){ v0=fmaxf(v0,0.f); v1=fmaxf(v1,0.f); v2=fmaxf(v2,0.f); v3=fmaxf(v3,0.f); }
        acc += __int_as_float(p0.y)*v0 + __int_as_float(p1.y)*v1
             + __int_as_float(p2.y)*v2 + __int_as_float(p3.y)*v3;
    }
    for (; e < e_end; e++){
        int2 pr = sorted[e];
        float v = src[(size_t)pr.x*64 + lane];
        if (RELU) v = fmaxf(v, 0.f);
        acc += __int_as_float(pr.y)*v;
    }
    outp[(size_t)node*64 + lane] = acc;
}

// ---------------- layer-2 projection: z = agg@W2 + b2 (8 nodes/block) ----------------
__global__ __launch_bounds__(256) void k_proj(const float* __restrict__ agg, const float* __restrict__ W2,
        const float* __restrict__ b2, float* __restrict__ z, int N){
    __shared__ float Ws[64*128];
    __shared__ float zs[2][68];
    int tid = threadIdx.x;
    for (int i = tid; i < 64*128; i += 256) Ws[i] = W2[i];
    int sub = tid >> 7, lane = tid & 127;
    float bb = b2[lane];
    #pragma unroll
    for (int p = 0; p < 4; p++){
        int node = blockIdx.x*8 + p*2 + sub;
        __syncthreads();                       // Ws ready (p==0) / prev compute done
        if (node < N && lane < 64) zs[sub][lane] = agg[(size_t)node*64 + lane];
        __syncthreads();
        if (node < N){
            float acc = bb;
            #pragma unroll 4
            for (int k = 0; k < 64; k++) acc += zs[sub][k] * Ws[k*128 + lane];
            z[(size_t)node*128 + lane] = acc;
        }
    }
}

// ---------------- build x = [z[seq] | dur_emb] ----------------
__global__ void k_build_x(const float* __restrict__ z, const int* __restrict__ seq,
        const float* __restrict__ dur, const float* __restrict__ dW1, const float* __restrict__ db1,
        const float* __restrict__ dW2, const float* __restrict__ db2, float* __restrict__ x){
    int row = blockIdx.x;
    int tid = threadIdx.x;       // 192 threads
    if (tid < 128){
        int node = seq[row];
        x[row*160 + tid] = z[node*128 + tid];
    } else if (tid < 160){
        int jj = tid - 128;
        float ld = log1pf(dur[row]);
        float acc = db2[jj];
        #pragma unroll
        for (int hh = 0; hh < 16; hh++){
            float hv = fmaxf(ld * dW1[hh] + db1[hh], 0.f);
            acc += hv * dW2[hh*32 + jj];
        }
        x[row*160 + tid] = acc;
    }
}

// ---------------- transpose Wih (512x160 -> 160x512), both dirs ----------------
__global__ void k_transpose_wih(const float* __restrict__ Wf, const float* __restrict__ Wb,
        float* __restrict__ Tf, float* __restrict__ Tb){
    int idx = blockIdx.x*256 + threadIdx.x;
    if (idx < 512*160){
        int g = idx / 160, k = idx % 160;
        Tf[k*512 + g] = Wf[idx];
        Tb[k*512 + g] = Wb[idx];
    }
}

// ---------------- generic f32 GEMM: C[M,N] = A[M,K] @ B[K,N] + bias[N] ----------------
#define MT 64
#define NT 128
#define KC 16
__global__ __launch_bounds__(256) void k_gemm(const float* __restrict__ A, const float* __restrict__ B,
        const float* __restrict__ bias, float* __restrict__ C, int M, int Nn, int K){
    __shared__ float As[KC][MT+4];
    __shared__ float Bs[KC][NT+4];
    int tid = threadIdx.x;
    int n0 = blockIdx.x * NT;
    int m0 = blockIdx.y * MT;
    int tn = tid & 31;
    int tm = tid >> 5;
    v2f acc[8][2];                       // packed fp32 pairs -> v_pk_fma_f32
    #pragma unroll
    for (int i = 0; i < 8; i++){ acc[i][0] = (v2f){0.f,0.f}; acc[i][1] = (v2f){0.f,0.f}; }

    for (int kt = 0; kt < K; kt += KC){
        {
            int m = tid >> 2, q = tid & 3;
            float4 a4 = *(const float4*)(A + (size_t)(m0+m)*K + kt + q*4);
            As[q*4+0][m] = a4.x; As[q*4+1][m] = a4.y; As[q*4+2][m] = a4.z; As[q*4+3][m] = a4.w;
        }
        {
            #pragma unroll
            for (int i = 0; i < 2; i++){
                int idx = tid*2 + i;
                int r = idx >> 5, c4 = idx & 31;
                int col = n0 + c4*4;
                float4 bv = make_float4(0.f,0.f,0.f,0.f);
                if (col < Nn) bv = *(const float4*)(B + (size_t)(kt+r)*Nn + col);
                *(float4*)(&Bs[r][c4*4]) = bv;
            }
        }
        __syncthreads();
        #pragma unroll
        for (int k = 0; k < KC; k++){
            float4 b4 = *(const float4*)(&Bs[k][tn*4]);
            v2f b01 = (v2f){b4.x, b4.y};
            v2f b23 = (v2f){b4.z, b4.w};
            float4 a0 = *(const float4*)(&As[k][tm*8]);
            float4 a1 = *(const float4*)(&As[k][tm*8+4]);
            float av[8] = {a0.x,a0.y,a0.z,a0.w,a1.x,a1.y,a1.z,a1.w};
            #pragma unroll
            for (int i = 0; i < 8; i++){
                v2f ai = (v2f){av[i], av[i]};
                acc[i][0] = __builtin_elementwise_fma(ai, b01, acc[i][0]);
                acc[i][1] = __builtin_elementwise_fma(ai, b23, acc[i][1]);
            }
        }
        __syncthreads();
    }
    int col = n0 + tn*4;
    if (col < Nn){
        float4 bb = *(const float4*)(bias + col);
        #pragma unroll
        for (int i = 0; i < 8; i++){
            int row = m0 + tm*8 + i;
            float4 o = make_float4(acc[i][0].x+bb.x, acc[i][0].y+bb.y, acc[i][1].x+bb.z, acc[i][1].y+bb.w);
            *(float4*)(C + (size_t)row*Nn + col) = o;
        }
    }
}

// ---------------- job sort: order (row,dir) jobs by descending length (LPT) ----------------
__global__ __launch_bounds__(512) void k_sortjobs(const int* __restrict__ lengths,
        int* __restrict__ jobs, int* __restrict__ counter){
    __shared__ int keys[512];
    __shared__ int vals[512];
    int tid = threadIdx.x;
    keys[tid] = -lengths[tid >> 1];     // ascending sort of -len == descending len
    vals[tid] = tid;
    __syncthreads();
    for (int k = 2; k <= 512; k <<= 1){
        for (int jj = k >> 1; jj > 0; jj >>= 1){
            int ixj = tid ^ jj;
            if (ixj > tid){
                bool up = ((tid & k) == 0);
                int k0 = keys[tid], k1 = keys[ixj];
                if ((k0 > k1) == up){
                    keys[tid] = k1; keys[ixj] = k0;
                    int v0 = vals[tid]; vals[tid] = vals[ixj]; vals[ixj] = v0;
                }
            }
            __syncthreads();
        }
    }
    jobs[tid] = vals[tid];
    if (tid == 0) *counter = 0;
}

// ---------------- LSTM recurrence: one block per job = (batch row, direction) ----------------
__global__ __launch_bounds__(512, 1) void k_lstm(const float* __restrict__ xg_f, const float* __restrict__ xg_b,
        const float* __restrict__ Whh_f, const float* __restrict__ Whh_b,
        const int* __restrict__ lengths, const int* __restrict__ jobs, int* __restrict__ counter,
        float* __restrict__ lstm_out, int T){
    __shared__ int job_s;
    int j = threadIdx.x;
    if (j == 0) job_s = atomicAdd(counter, 1);
    __syncthreads();
    int job = jobs[job_s];
    int b = job >> 1, dir = job & 1;
    const float* xg  = dir ? xg_b  : xg_f;
    const float* Whh = dir ? Whh_b : Whh_f;
    int len = lengths[b];
    __shared__ __align__(16) float h[128];
    __shared__ float g[512];
    v2f w[64];                                   // full Whh row: 128 VGPRs
    const v2f* wrow = (const v2f*)(Whh + j*128);
    #pragma unroll
    for (int k = 0; k < 64; k++) w[k] = wrow[k];
    if (j < 128) h[j] = 0.f;
    float c = 0.f;
    const float* xgb = xg + (size_t)b*T*512 + j;
    float* lob = lstm_out + (size_t)b*T*256 + dir*128 + j;
    int t0 = dir ? (len-1) : 0;
    float xg_next = xgb[(size_t)t0*512];
    __syncthreads();
    for (int s = 0; s < len; s++){
        int t = dir ? (len-1-s) : s;
        float xgv = xg_next;
        if (s+1 < len){
            int tn = dir ? (len-2-s) : (s+1);
            xg_next = xgb[(size_t)tn*512];      // prefetch next step's gate input
        }
        const float4* h4 = (const float4*)h;
        v2f p0 = (v2f){0.f,0.f}, p1 = (v2f){0.f,0.f}, p2 = (v2f){0.f,0.f}, p3 = (v2f){0.f,0.f};
        #pragma unroll
        for (int k = 0; k < 32; k += 2){
            float4 ha = h4[k+0];
            float4 hb = h4[k+1];
            p0 = __builtin_elementwise_fma(w[2*k+0], (v2f){ha.x,ha.y}, p0);
            p1 = __builtin_elementwise_fma(w[2*k+1], (v2f){ha.z,ha.w}, p1);
            p2 = __builtin_elementwise_fma(w[2*k+2], (v2f){hb.x,hb.y}, p2);
            p3 = __builtin_elementwise_fma(w[2*k+3], (v2f){hb.z,hb.w}, p3);
        }
        g[j] = xgv + (((p0.x+p0.y)+(p1.x+p1.y)) + ((p2.x+p2.y)+(p3.x+p3.y)));
        __syncthreads();
        if (j < 128){
            float gi = g[j], gf = g[128+j], gg = g[256+j], go = g[384+j];
            float cn = sigmf(gf)*c + sigmf(gi)*tanh_f(gg);
            float hn = sigmf(go)*tanh_f(cn);
            c = cn;
            h[j] = hn;
            lob[(size_t)t*256] = hn;
        }
        __syncthreads();
    }
}

// ---------------- attention + context ----------------
__global__ __launch_bounds__(256) void k_attn(const float* __restrict__ lstm_out,
        const float* __restrict__ attn_W, const int* __restrict__ lengths,
        float* __restrict__ context, int T){
    int b = blockIdx.x;
    int tid = threadIdx.x;
    int len = lengths[b];
    __shared__ float sc[TSEQ_MAX];
    __shared__ float red[8];
    int lane = tid & 63, wv = tid >> 6;
    float a0 = attn_W[lane], a1 = attn_W[64+lane], a2 = attn_W[128+lane], a3 = attn_W[192+lane];
    for (int t = wv; t < len; t += 4){
        const float* r = lstm_out + ((size_t)b*T + t)*256;
        float p = r[lane]*a0 + r[64+lane]*a1 + r[128+lane]*a2 + r[192+lane]*a3;
        #pragma unroll
        for (int o = 32; o > 0; o >>= 1) p += __shfl_down(p, o);
        if (lane == 0) sc[t] = p;
    }
    __syncthreads();
    float v = (tid < len) ? sc[tid] : -INFINITY;
    float m = v;
    #pragma unroll
    for (int o = 32; o > 0; o >>= 1) m = fmaxf(m, __shfl_down(m, o));
    if (lane == 0) red[wv] = m;
    __syncthreads();
    float M4 = fmaxf(fmaxf(red[0],red[1]), fmaxf(red[2],red[3]));
    float e = (tid < len) ? __expf(v - M4) : 0.f;
    float ss = e;
    #pragma unroll
    for (int o = 32; o > 0; o >>= 1) ss += __shfl_down(ss, o);
    if (lane == 0) red[4+wv] = ss;
    __syncthreads();
    float S = red[4]+red[5]+red[6]+red[7];
    sc[tid] = e / S;
    __syncthreads();
    float acc = 0.f;
    for (int t = 0; t < len; t++) acc += sc[t] * lstm_out[((size_t)b*T + t)*256 + tid];
    context[b*256 + tid] = acc;
}

extern "C" void kernel_launch(void* const* d_in, const int* in_sizes, int n_in,
                              void* d_out, int out_size, void* d_ws, size_t ws_size,
                              hipStream_t stream) {
    const float* x_coords  = (const float*)d_in[0];
    const float* temporal  = (const float*)d_in[1];
    const int*   edge_idx  = (const int*)  d_in[2];
    const float* edge_w    = (const float*)d_in[3];
    const int*   seq       = (const int*)  d_in[4];
    const float* durations = (const float*)d_in[5];
    const int*   lengths   = (const int*)  d_in[6];
    const float* node_emb  = (const float*)d_in[7];
    const float* gcn1_W    = (const float*)d_in[8];
    const float* gcn1_b    = (const float*)d_in[9];
    const float* gcn2_W    = (const float*)d_in[10];
    const float* gcn2_b    = (const float*)d_in[11];
    const float* dur_W1    = (const float*)d_in[12];
    const float* dur_b1    = (const float*)d_in[13];
    const float* dur_W2    = (const float*)d_in[14];
    const float* dur_b2    = (const float*)d_in[15];
    const float* Wih_f     = (const float*)d_in[16];
    const float* Whh_f     = (const float*)d_in[17];
    const float* b_f       = (const float*)d_in[18];
    const float* Wih_b     = (const float*)d_in[19];
    const float* Whh_b     = (const float*)d_in[20];
    const float* b_b       = (const float*)d_in[21];
    const float* attn_W    = (const float*)d_in[22];
    const float* fc_W      = (const float*)d_in[24];
    const float* fc_b      = (const float*)d_in[25];
    float* out = (float*)d_out;
    float* ws  = (float*)d_ws;

    const int N  = in_sizes[0] / 2;      // 100000
    const int E  = in_sizes[2] / 2;      // 1600000
    const int B  = in_sizes[6];          // 256
    const int T  = in_sizes[4] / B;      // 200
    const int BT = B * T;                // 51200

    // persistent region (floats)
    float* xg_f     = ws + 0;                       // 26,214,400
    float* xg_b     = ws + 26214400;                // 26,214,400
    float* xbuf     = ws + 52428800;                //  8,192,000
    float* lstm_out = ws + 60620800;                // 13,107,200
    float* context  = ws + 73728000;                //     65,536
    float* WihT_f   = ws + 73793536;                //     81,920
    float* WihT_b   = ws + 73875456;                //     81,920  (total ~296 MB)

    // jobs/counter live in the context region: written by k_sortjobs early,
    // consumed by k_lstm, dead before k_attn writes context.
    int* jobs    = (int*)context;          // 512 ints
    int* counter = (int*)context + 512;    // 1 int

    // GCN temporaries overlaid under xg region (all dead before GEMMs write xg)
    float* dis  = ws + 0;            // N
    float* xw1  = ws + 100352;       // N*64
    float* out1 = ws + 6500352;      // N*64
    float* agg  = ws + 12900352;     // N*64   (layer-2 pre-projection aggregate)
    float* zbuf = ws + 25700352;     // N*128  (ends 38,500,352)
    int2*  sorted   = (int2*)(ws + 38500352);   // E * 8B
    int*   cnt      = (int*) (ws + 41700352);   // N
    int*   base     = (int*) (ws + 41800352);   // N+1
    int*   cursor   = (int*) (ws + 41900356);   // N
    int*   partials = (int*) (ws + 42000356);   // 128

    const int SCAN_BLOCKS = (N + 1023) / 1024;  // 98

    // ---- job ordering for LSTM load balance ----
    k_sortjobs<<<dim3(1), dim3(512), 0, stream>>>(lengths, jobs, counter);

    // ---- GCN normalization ----
    k_deg_init<<<dim3((N+255)/256), dim3(256), 0, stream>>>(dis, N);
    k_deg_acc <<<dim3((E+255)/256), dim3(256), 0, stream>>>(edge_idx, edge_w, dis, E);
    k_dis     <<<dim3((N+255)/256), dim3(256), 0, stream>>>(dis, N);

    // ---- CSR build (sort edges by destination) ----
    hipMemsetAsync(cnt, 0, (size_t)N*sizeof(int), stream);
    k_count  <<<dim3((E+255)/256), dim3(256), 0, stream>>>(edge_idx, cnt, E);
    k_scan1  <<<dim3(SCAN_BLOCKS), dim3(256), 0, stream>>>(cnt, base, partials, N);
    k_scan2  <<<dim3(1), dim3(128), 0, stream>>>(partials, SCAN_BLOCKS);
    k_scan3  <<<dim3((N+256)/256), dim3(256), 0, stream>>>(base, cursor, partials, N, E);
    k_scatter<<<dim3((E+255)/256), dim3(256), 0, stream>>>(edge_idx, edge_w, dis, cursor, sorted, E);

    // ---- GCN layer 1 ----
    k_xw1<<<dim3((N+3)/4), dim3(256), 0, stream>>>(x_coords, temporal, node_emb, gcn1_W, xw1, N);
    k_gather64<false><<<dim3((N+3)/4), dim3(256), 0, stream>>>(sorted, base, dis, xw1, gcn1_b, out1, N);

    // ---- GCN layer 2: aggregate relu(out1) in 64-dim, THEN project to 128 ----
    k_gather64<true><<<dim3((N+3)/4), dim3(256), 0, stream>>>(sorted, base, dis, out1, nullptr, agg, N);
    k_proj<<<dim3((N+7)/8), dim3(256), 0, stream>>>(agg, gcn2_W, gcn2_b, zbuf, N);

    // ---- sequence features ----
    k_build_x<<<dim3(BT), dim3(192), 0, stream>>>(zbuf, seq, durations, dur_W1, dur_b1, dur_W2, dur_b2, xbuf);

    // ---- input-gate GEMMs ----
    k_transpose_wih<<<dim3(320), dim3(256), 0, stream>>>(Wih_f, Wih_b, WihT_f, WihT_b);
    k_gemm<<<dim3(512/NT, BT/MT), dim3(256), 0, stream>>>(xbuf, WihT_f, b_f, xg_f, BT, 512, 160);
    k_gemm<<<dim3(512/NT, BT/MT), dim3(256), 0, stream>>>(xbuf, WihT_b, b_b, xg_b, BT, 512, 160);

    // ---- BiLSTM recurrence (LPT job order) ----
    k_lstm<<<dim3(2*B), dim3(512), 0, stream>>>(xg_f, xg_b, Whh_f, Whh_b, lengths, jobs, counter, lstm_out, T);

    // ---- attention ----
    k_attn<<<dim3(B), dim3(256), 0, stream>>>(lstm_out, attn_W, lengths, context, T);

    // ---- final FC: (256 x 256) @ (256 x 100000) + fc_b ----
    k_gemm<<<dim3((N + NT - 1)/NT, B/MT), dim3(256), 0, stream>>>(context, fc_W, fc_b, out, B, N, 256);
}

// Round 2
// 1453.559 us; speedup vs baseline: 1.2464x; 1.0330x over previous
//
#include <hip/hip_runtime.h>
#include <math.h>

#define TSEQ_MAX 256

typedef float v2f __attribute__((ext_vector_type(2)));

__device__ __forceinline__ float sigmf(float x){ return 1.f/(1.f+__expf(-x)); }
__device__ __forceinline__ float tanh_f(float x){ return 1.f - 2.f/(__expf(2.f*x)+1.f); }

// ---------------- GCN degree / norm ----------------
__global__ void k_deg_init(float* deg, int N){
    int i = blockIdx.x*256 + threadIdx.x;
    if (i < N) deg[i] = 1.0f;              // self-loop weight
}
__global__ void k_deg_acc(const int* __restrict__ ei, const float* __restrict__ ew, float* deg, int E){
    int e = blockIdx.x*256 + threadIdx.x;
    if (e < E) atomicAdd(&deg[ei[E + e]], ew[e]);
}
__global__ void k_dis(float* deg, int N){
    int i = blockIdx.x*256 + threadIdx.x;
    if (i < N){ float d = deg[i]; deg[i] = (d > 0.f) ? rsqrtf(fmaxf(d, 1e-12f)) : 0.f; }
}

// ---------------- CSR build: count, scan, scatter ----------------
__global__ void k_count(const int* __restrict__ ei, int* __restrict__ cnt, int E){
    int e = blockIdx.x*256 + threadIdx.x;
    if (e < E) atomicAdd(&cnt[ei[E + e]], 1);
}

__global__ __launch_bounds__(256) void k_scan1(const int* __restrict__ cnt, int* __restrict__ base,
        int* __restrict__ partials, int N){
    __shared__ int sh[256];
    int tid = threadIdx.x;
    int i0 = blockIdx.x*1024 + tid*4;
    int v0=0,v1=0,v2=0,v3=0;
    if (i0+0 < N) v0 = cnt[i0+0];
    if (i0+1 < N) v1 = cnt[i0+1];
    if (i0+2 < N) v2 = cnt[i0+2];
    if (i0+3 < N) v3 = cnt[i0+3];
    int tsum = v0+v1+v2+v3;
    sh[tid] = tsum;
    __syncthreads();
    for (int off = 1; off < 256; off <<= 1){
        int val = (tid >= off) ? sh[tid-off] : 0;
        __syncthreads();
        sh[tid] += val;
        __syncthreads();
    }
    int excl = sh[tid] - tsum;
    if (i0+0 < N) base[i0+0] = excl;
    if (i0+1 < N) base[i0+1] = excl + v0;
    if (i0+2 < N) base[i0+2] = excl + v0 + v1;
    if (i0+3 < N) base[i0+3] = excl + v0 + v1 + v2;
    if (tid == 255) partials[blockIdx.x] = sh[255];
}
__global__ __launch_bounds__(128) void k_scan2(int* partials, int nb){
    __shared__ int sh[128];
    int tid = threadIdx.x;
    int v = (tid < nb) ? partials[tid] : 0;
    sh[tid] = v;
    __syncthreads();
    for (int off = 1; off < 128; off <<= 1){
        int val = (tid >= off) ? sh[tid-off] : 0;
        __syncthreads();
        sh[tid] += val;
        __syncthreads();
    }
    if (tid < nb) partials[tid] = sh[tid] - v;   // exclusive
}
__global__ void k_scan3(int* base, int* cursor, const int* __restrict__ partials, int N, int E){
    int i = blockIdx.x*256 + threadIdx.x;
    if (i < N){
        int v = base[i] + partials[i >> 10];
        base[i] = v; cursor[i] = v;
    }
    if (i == N) base[N] = E;
}
__global__ void k_scatter(const int* __restrict__ ei, const float* __restrict__ ew,
        const float* __restrict__ dis, int* cursor, int2* __restrict__ sorted, int E){
    int e = blockIdx.x*256 + threadIdx.x;
    if (e < E){
        int r = ei[e], c = ei[E + e];
        float nrm = dis[r] * ew[e] * dis[c];
        int pos = atomicAdd(&cursor[c], 1);
        sorted[pos] = make_int2(r, __float_as_int(nrm));
    }
}

// ---------------- GCN layer 1: xw1 = feats@W1 ----------------
__global__ __launch_bounds__(256) void k_xw1(const float* __restrict__ xc, const float* __restrict__ te,
        const float* __restrict__ emb, const float* __restrict__ W1,
        float* __restrict__ xw1, int N){
    __shared__ float Ws[134*64];
    __shared__ float fs[4][136];
    int tid = threadIdx.x;
    for (int i = tid; i < 134*64; i += 256) Ws[i] = W1[i];
    int sub = tid >> 6, lane = tid & 63;
    int node = blockIdx.x*4 + sub;
    if (node < N){
        fs[sub][2+lane]      = emb[node*128 + lane];
        fs[sub][2+64+lane]   = emb[node*128 + 64 + lane];
        if (lane < 2) fs[sub][lane]       = xc[node*2 + lane];
        if (lane < 4) fs[sub][130 + lane] = te[node*4 + lane];
    }
    __syncthreads();
    if (node < N){
        float acc = 0.f;
        #pragma unroll 2
        for (int k = 0; k < 134; k++) acc += fs[sub][k] * Ws[k*64 + lane];
        xw1[node*64 + lane] = acc;
    }
}

// ---------------- CSR gather, 64 channels, unroll-4 for MLP ----------------
template<bool RELU>
__global__ __launch_bounds__(256) void k_gather64(const int2* __restrict__ sorted, const int* __restrict__ base,
        const float* __restrict__ dis, const float* __restrict__ src, const float* __restrict__ b,
        float* __restrict__ outp, int N){
    int node = blockIdx.x*4 + (threadIdx.x >> 6);
    int lane = threadIdx.x & 63;
    if (node >= N) return;
    int s = base[node], e_end = base[node+1];
    float d = dis[node];
    float self = src[(size_t)node*64 + lane];
    if (RELU) self = fmaxf(self, 0.f);
    float acc = d*d*self;
    if (!RELU) acc += b[lane];
    int e = s;
    for (; e + 4 <= e_end; e += 4){
        int2 p0 = sorted[e+0];
        int2 p1 = sorted[e+1];
        int2 p2 = sorted[e+2];
        int2 p3 = sorted[e+3];
        float v0 = src[(size_t)p0.x*64 + lane];
        float v1 = src[(size_t)p1.x*64 + lane];
        float v2 = src[(size_t)p2.x*64 + lane];
        float v3 = src[(size_t)p3.x*64 + lane];
        if (RELU){ v0=fmaxf(v0,0.f); v1=fmaxf(v1,0.f); v2=fmaxf(v2,0.f); v3=fmaxf(v3,0.f); }
        acc += __int_as_float(p0.y)*v0 + __int_as_float(p1.y)*v1
             + __int_as_float(p2.y)*v2 + __int_as_float(p3.y)*v3;
    }
    for (; e < e_end; e++){
        int2 pr = sorted[e];
        float v = src[(size_t)pr.x*64 + lane];
        if (RELU) v = fmaxf(v, 0.f);
        acc += __int_as_float(pr.y)*v;
    }
    outp[(size_t)node*64 + lane] = acc;
}

// ---------------- layer-2 projection: z = agg@W2 + b2 (8 nodes/block) ----------------
__global__ __launch_bounds__(256) void k_proj(const float* __restrict__ agg, const float* __restrict__ W2,
        const float* __restrict__ b2, float* __restrict__ z, int N){
    __shared__ float Ws[64*128];
    __shared__ float zs[2][68];
    int tid = threadIdx.x;
    for (int i = tid; i < 64*128; i += 256) Ws[i] = W2[i];
    int sub = tid >> 7, lane = tid & 127;
    float bb = b2[lane];
    #pragma unroll
    for (int p = 0; p < 4; p++){
        int node = blockIdx.x*8 + p*2 + sub;
        __syncthreads();
        if (node < N && lane < 64) zs[sub][lane] = agg[(size_t)node*64 + lane];
        __syncthreads();
        if (node < N){
            float acc = bb;
            #pragma unroll 4
            for (int k = 0; k < 64; k++) acc += zs[sub][k] * Ws[k*128 + lane];
            z[(size_t)node*128 + lane] = acc;
        }
    }
}

// ---------------- build x = [z[seq] | dur_emb] ----------------
__global__ void k_build_x(const float* __restrict__ z, const int* __restrict__ seq,
        const float* __restrict__ dur, const float* __restrict__ dW1, const float* __restrict__ db1,
        const float* __restrict__ dW2, const float* __restrict__ db2, float* __restrict__ x){
    int row = blockIdx.x;
    int tid = threadIdx.x;       // 192 threads
    if (tid < 128){
        int node = seq[row];
        x[row*160 + tid] = z[node*128 + tid];
    } else if (tid < 160){
        int jj = tid - 128;
        float ld = log1pf(dur[row]);
        float acc = db2[jj];
        #pragma unroll
        for (int hh = 0; hh < 16; hh++){
            float hv = fmaxf(ld * dW1[hh] + db1[hh], 0.f);
            acc += hv * dW2[hh*32 + jj];
        }
        x[row*160 + tid] = acc;
    }
}

// ---------------- transpose Wih (512x160 -> 160x512), both dirs ----------------
__global__ void k_transpose_wih(const float* __restrict__ Wf, const float* __restrict__ Wb,
        float* __restrict__ Tf, float* __restrict__ Tb){
    int idx = blockIdx.x*256 + threadIdx.x;
    if (idx < 512*160){
        int g = idx / 160, k = idx % 160;
        Tf[k*512 + g] = Wf[idx];
        Tb[k*512 + g] = Wb[idx];
    }
}

// ---------------- generic f32 GEMM: C[M,N] = A[M,K] @ B[K,N] + bias[N] ----------------
#define MT 64
#define NT 128
#define KC 16
__global__ __launch_bounds__(256) void k_gemm(const float* __restrict__ A, const float* __restrict__ B,
        const float* __restrict__ bias, float* __restrict__ C, int M, int Nn, int K){
    __shared__ float As[KC][MT+4];
    __shared__ float Bs[KC][NT+4];
    int tid = threadIdx.x;
    int n0 = blockIdx.x * NT;
    int m0 = blockIdx.y * MT;
    int tn = tid & 31;
    int tm = tid >> 5;
    v2f acc[8][2];
    #pragma unroll
    for (int i = 0; i < 8; i++){ acc[i][0] = (v2f){0.f,0.f}; acc[i][1] = (v2f){0.f,0.f}; }

    for (int kt = 0; kt < K; kt += KC){
        {
            int m = tid >> 2, q = tid & 3;
            float4 a4 = *(const float4*)(A + (size_t)(m0+m)*K + kt + q*4);
            As[q*4+0][m] = a4.x; As[q*4+1][m] = a4.y; As[q*4+2][m] = a4.z; As[q*4+3][m] = a4.w;
        }
        {
            #pragma unroll
            for (int i = 0; i < 2; i++){
                int idx = tid*2 + i;
                int r = idx >> 5, c4 = idx & 31;
                int col = n0 + c4*4;
                float4 bv = make_float4(0.f,0.f,0.f,0.f);
                if (col < Nn) bv = *(const float4*)(B + (size_t)(kt+r)*Nn + col);
                *(float4*)(&Bs[r][c4*4]) = bv;
            }
        }
        __syncthreads();
        #pragma unroll
        for (int k = 0; k < KC; k++){
            float4 b4 = *(const float4*)(&Bs[k][tn*4]);
            v2f b01 = (v2f){b4.x, b4.y};
            v2f b23 = (v2f){b4.z, b4.w};
            float4 a0 = *(const float4*)(&As[k][tm*8]);
            float4 a1 = *(const float4*)(&As[k][tm*8+4]);
            float av[8] = {a0.x,a0.y,a0.z,a0.w,a1.x,a1.y,a1.z,a1.w};
            #pragma unroll
            for (int i = 0; i < 8; i++){
                v2f ai = (v2f){av[i], av[i]};
                acc[i][0] = __builtin_elementwise_fma(ai, b01, acc[i][0]);
                acc[i][1] = __builtin_elementwise_fma(ai, b23, acc[i][1]);
            }
        }
        __syncthreads();
    }
    int col = n0 + tn*4;
    if (col < Nn){
        float4 bb = *(const float4*)(bias + col);
        #pragma unroll
        for (int i = 0; i < 8; i++){
            int row = m0 + tm*8 + i;
            float4 o = make_float4(acc[i][0].x+bb.x, acc[i][0].y+bb.y, acc[i][1].x+bb.z, acc[i][1].y+bb.w);
            *(float4*)(C + (size_t)row*Nn + col) = o;
        }
    }
}

// ---------------- job sort: order (row,dir) jobs by descending length (LPT) ----------------
__global__ __launch_bounds__(512) void k_sortjobs(const int* __restrict__ lengths,
        int* __restrict__ jobs, int* __restrict__ counter){
    __shared__ int keys[512];
    __shared__ int vals[512];
    int tid = threadIdx.x;
    keys[tid] = -lengths[tid >> 1];
    vals[tid] = tid;
    __syncthreads();
    for (int k = 2; k <= 512; k <<= 1){
        for (int jj = k >> 1; jj > 0; jj >>= 1){
            int ixj = tid ^ jj;
            if (ixj > tid){
                bool up = ((tid & k) == 0);
                int k0 = keys[tid], k1 = keys[ixj];
                if ((k0 > k1) == up){
                    keys[tid] = k1; keys[ixj] = k0;
                    int v0 = vals[tid]; vals[tid] = vals[ixj]; vals[ixj] = v0;
                }
            }
            __syncthreads();
        }
    }
    jobs[tid] = vals[tid];
    if (tid == 0) *counter = 0;
}

// ---------------- LSTM recurrence v2 ----------------
// 1024-thread persistent blocks, one job (row,dir) at a time via atomic counter
// (dynamic LPT). Per step: g = Whh@h split as thread(G=t>>3, s=t&7) computing
// 4 outputs (4G..4G+3) x 16 k (16s..16s+16): w = 64 VGPRs/thread (fits the
// 128-VGPR cap a 1024-thread block REQUIRES -> stays register-resident),
// h reads = 4x ds_read_b128/thread (64 instrs/step vs 256 before), <=2-way
// bank conflicts via h_pad[8][24]. 3-stage shfl_xor reduce lands output j=t's
// own slot. NOTE: Whh/lstm_out deliberately NOT __restrict: in-loop stores
// may alias Whh -> compiler cannot re-materialize weight loads inside the loop.
__global__ __launch_bounds__(1024, 4) void k_lstm(const float* __restrict__ xg_f, const float* __restrict__ xg_b,
        const float* Whh_f, const float* Whh_b,
        const int* __restrict__ lengths, const int* __restrict__ jobs, int* __restrict__ counter,
        float* lstm_out, int T, int NJOBS){
    __shared__ int job_s;
    __shared__ float h_pad[8*24];     // h[k] at h_pad[(k>>4)*24 + (k&15)]
    __shared__ float g_lds[512];
    int t = threadIdx.x;
    int Gq = t >> 3;                  // output group: outputs 4Gq..4Gq+3
    int s  = t & 7;                   // k-slice: k in [16s, 16s+16)
    bool wr = (s < 4);
    int jout = 4*Gq + s;              // valid when wr

    for (;;){
        if (t == 0) job_s = atomicAdd(counter, 1);
        __syncthreads();
        int js = job_s;
        if (js >= NJOBS) return;
        int job = jobs[js];
        int b = job >> 1, dir = job & 1;
        const float* xg  = dir ? xg_b  : xg_f;
        const float* Whh = dir ? Whh_b : Whh_f;
        int len = lengths[b];

        // load weight slice: rows 4Gq..4Gq+3, cols 16s..16s+16  (64 floats)
        v2f w[32];
        const float* wbase = Whh + (size_t)(4*Gq)*128 + 16*s;
        #pragma unroll
        for (int r = 0; r < 4; r++){
            const v2f* wrow = (const v2f*)(wbase + r*128);
            #pragma unroll
            for (int c = 0; c < 8; c++) w[r*8+c] = wrow[c];
        }

        if (t < 128) h_pad[(t>>4)*24 + (t&15)] = 0.f;
        float cst = 0.f;
        const float* xgb = xg + (size_t)b*T*512 + jout;
        float* lob = lstm_out + (size_t)b*T*256 + dir*128 + t;   // valid t<128
        int t0 = dir ? (len-1) : 0;
        float xg_next = 0.f;
        if (wr) xg_next = xgb[(size_t)t0*512];
        __syncthreads();

        for (int st = 0; st < len; st++){
            int tt = dir ? (len-1-st) : st;
            // ---- partial GEMV: 4 outputs x 16 k ----
            const float4* hp = (const float4*)(h_pad + s*24);
            v2f ac0 = (v2f){0.f,0.f}, ac1 = (v2f){0.f,0.f}, ac2 = (v2f){0.f,0.f}, ac3 = (v2f){0.f,0.f};
            #pragma unroll
            for (int c = 0; c < 4; c++){
                float4 hv = hp[c];
                v2f h01 = (v2f){hv.x, hv.y};
                v2f h23 = (v2f){hv.z, hv.w};
                ac0 = __builtin_elementwise_fma(w[0*8+2*c],   h01, ac0);
                ac0 = __builtin_elementwise_fma(w[0*8+2*c+1], h23, ac0);
                ac1 = __builtin_elementwise_fma(w[1*8+2*c],   h01, ac1);
                ac1 = __builtin_elementwise_fma(w[1*8+2*c+1], h23, ac1);
                ac2 = __builtin_elementwise_fma(w[2*8+2*c],   h01, ac2);
                ac2 = __builtin_elementwise_fma(w[2*8+2*c+1], h23, ac2);
                ac3 = __builtin_elementwise_fma(w[3*8+2*c],   h01, ac3);
                ac3 = __builtin_elementwise_fma(w[3*8+2*c+1], h23, ac3);
            }
            float a0 = ac0.x + ac0.y;
            float a1 = ac1.x + ac1.y;
            float a2 = ac2.x + ac2.y;
            float a3 = ac3.x + ac3.y;
            // ---- 3-stage reduce over 8 k-slices; lane s ends with output 4Gq+(s&3) ----
            int s1 = s & 1, s2 = (s >> 1) & 1;
            float b0 = (s1 ? a1 : a0) + __shfl_xor(s1 ? a0 : a1, 1);   // o = s1
            float b1 = (s1 ? a3 : a2) + __shfl_xor(s1 ? a2 : a3, 1);   // o = 2+s1
            float cs = (s2 ? b1 : b0) + __shfl_xor(s2 ? b0 : b1, 2);   // o = s&3
            float gsum = cs + __shfl_xor(cs, 4);                       // full k
            float xgv = xg_next;
            if (wr && st+1 < len){
                int tn = dir ? (len-2-st) : (st+1);
                xg_next = xgb[(size_t)tn*512];
            }
            if (wr) g_lds[jout] = gsum + xgv;
            __syncthreads();
            // ---- gates (threads 0..127) ----
            if (t < 128){
                float gi = g_lds[t], gf = g_lds[128+t], gg = g_lds[256+t], go = g_lds[384+t];
                float cn = sigmf(gf)*cst + sigmf(gi)*tanh_f(gg);
                float hn = sigmf(go)*tanh_f(cn);
                cst = cn;
                h_pad[(t>>4)*24 + (t&15)] = hn;
                lob[(size_t)tt*256] = hn;
            }
            __syncthreads();
        }
    }
}

// ---------------- attention + context ----------------
__global__ __launch_bounds__(256) void k_attn(const float* __restrict__ lstm_out,
        const float* __restrict__ attn_W, const int* __restrict__ lengths,
        float* __restrict__ context, int T){
    int b = blockIdx.x;
    int tid = threadIdx.x;
    int len = lengths[b];
    __shared__ float sc[TSEQ_MAX];
    __shared__ float red[8];
    int lane = tid & 63, wv = tid >> 6;
    float a0 = attn_W[lane], a1 = attn_W[64+lane], a2 = attn_W[128+lane], a3 = attn_W[192+lane];
    for (int t = wv; t < len; t += 4){
        const float* r = lstm_out + ((size_t)b*T + t)*256;
        float p = r[lane]*a0 + r[64+lane]*a1 + r[128+lane]*a2 + r[192+lane]*a3;
        #pragma unroll
        for (int o = 32; o > 0; o >>= 1) p += __shfl_down(p, o);
        if (lane == 0) sc[t] = p;
    }
    __syncthreads();
    float v = (tid < len) ? sc[tid] : -INFINITY;
    float m = v;
    #pragma unroll
    for (int o = 32; o > 0; o >>= 1) m = fmaxf(m, __shfl_down(m, o));
    if (lane == 0) red[wv] = m;
    __syncthreads();
    float M4 = fmaxf(fmaxf(red[0],red[1]), fmaxf(red[2],red[3]));
    float e = (tid < len) ? __expf(v - M4) : 0.f;
    float ss = e;
    #pragma unroll
    for (int o = 32; o > 0; o >>= 1) ss += __shfl_down(ss, o);
    if (lane == 0) red[4+wv] = ss;
    __syncthreads();
    float S = red[4]+red[5]+red[6]+red[7];
    sc[tid] = e / S;
    __syncthreads();
    float acc = 0.f;
    for (int t = 0; t < len; t++) acc += sc[t] * lstm_out[((size_t)b*T + t)*256 + tid];
    context[b*256 + tid] = acc;
}

extern "C" void kernel_launch(void* const* d_in, const int* in_sizes, int n_in,
                              void* d_out, int out_size, void* d_ws, size_t ws_size,
                              hipStream_t stream) {
    const float* x_coords  = (const float*)d_in[0];
    const float* temporal  = (const float*)d_in[1];
    const int*   edge_idx  = (const int*)  d_in[2];
    const float* edge_w    = (const float*)d_in[3];
    const int*   seq       = (const int*)  d_in[4];
    const float* durations = (const float*)d_in[5];
    const int*   lengths   = (const int*)  d_in[6];
    const float* node_emb  = (const float*)d_in[7];
    const float* gcn1_W    = (const float*)d_in[8];
    const float* gcn1_b    = (const float*)d_in[9];
    const float* gcn2_W    = (const float*)d_in[10];
    const float* gcn2_b    = (const float*)d_in[11];
    const float* dur_W1    = (const float*)d_in[12];
    const float* dur_b1    = (const float*)d_in[13];
    const float* dur_W2    = (const float*)d_in[14];
    const float* dur_b2    = (const float*)d_in[15];
    const float* Wih_f     = (const float*)d_in[16];
    const float* Whh_f     = (const float*)d_in[17];
    const float* b_f       = (const float*)d_in[18];
    const float* Wih_b     = (const float*)d_in[19];
    const float* Whh_b     = (const float*)d_in[20];
    const float* b_b       = (const float*)d_in[21];
    const float* attn_W    = (const float*)d_in[22];
    const float* fc_W      = (const float*)d_in[24];
    const float* fc_b      = (const float*)d_in[25];
    float* out = (float*)d_out;
    float* ws  = (float*)d_ws;

    const int N  = in_sizes[0] / 2;      // 100000
    const int E  = in_sizes[2] / 2;      // 1600000
    const int B  = in_sizes[6];          // 256
    const int T  = in_sizes[4] / B;      // 200
    const int BT = B * T;                // 51200

    // persistent region (floats)
    float* xg_f     = ws + 0;                       // 26,214,400
    float* xg_b     = ws + 26214400;                // 26,214,400
    float* xbuf     = ws + 52428800;                //  8,192,000
    float* lstm_out = ws + 60620800;                // 13,107,200
    float* context  = ws + 73728000;                //     65,536
    float* WihT_f   = ws + 73793536;                //     81,920
    float* WihT_b   = ws + 73875456;                //     81,920

    int* jobs    = (int*)context;          // 512 ints
    int* counter = (int*)context + 512;    // 1 int

    // GCN temporaries overlaid under xg region (all dead before GEMMs write xg)
    float* dis  = ws + 0;            // N
    float* xw1  = ws + 100352;       // N*64
    float* out1 = ws + 6500352;      // N*64
    float* agg  = ws + 12900352;     // N*64
    float* zbuf = ws + 25700352;     // N*128
    int2*  sorted   = (int2*)(ws + 38500352);   // E * 8B
    int*   cnt      = (int*) (ws + 41700352);   // N
    int*   base     = (int*) (ws + 41800352);   // N+1
    int*   cursor   = (int*) (ws + 41900356);   // N
    int*   partials = (int*) (ws + 42000356);   // 128

    const int SCAN_BLOCKS = (N + 1023) / 1024;  // 98

    // ---- job ordering for LSTM load balance ----
    k_sortjobs<<<dim3(1), dim3(512), 0, stream>>>(lengths, jobs, counter);

    // ---- GCN normalization ----
    k_deg_init<<<dim3((N+255)/256), dim3(256), 0, stream>>>(dis, N);
    k_deg_acc <<<dim3((E+255)/256), dim3(256), 0, stream>>>(edge_idx, edge_w, dis, E);
    k_dis     <<<dim3((N+255)/256), dim3(256), 0, stream>>>(dis, N);

    // ---- CSR build (sort edges by destination) ----
    hipMemsetAsync(cnt, 0, (size_t)N*sizeof(int), stream);
    k_count  <<<dim3((E+255)/256), dim3(256), 0, stream>>>(edge_idx, cnt, E);
    k_scan1  <<<dim3(SCAN_BLOCKS), dim3(256), 0, stream>>>(cnt, base, partials, N);
    k_scan2  <<<dim3(1), dim3(128), 0, stream>>>(partials, SCAN_BLOCKS);
    k_scan3  <<<dim3((N+256)/256), dim3(256), 0, stream>>>(base, cursor, partials, N, E);
    k_scatter<<<dim3((E+255)/256), dim3(256), 0, stream>>>(edge_idx, edge_w, dis, cursor, sorted, E);

    // ---- GCN layer 1 ----
    k_xw1<<<dim3((N+3)/4), dim3(256), 0, stream>>>(x_coords, temporal, node_emb, gcn1_W, xw1, N);
    k_gather64<false><<<dim3((N+3)/4), dim3(256), 0, stream>>>(sorted, base, dis, xw1, gcn1_b, out1, N);

    // ---- GCN layer 2: aggregate relu(out1) in 64-dim, THEN project to 128 ----
    k_gather64<true><<<dim3((N+3)/4), dim3(256), 0, stream>>>(sorted, base, dis, out1, nullptr, agg, N);
    k_proj<<<dim3((N+7)/8), dim3(256), 0, stream>>>(agg, gcn2_W, gcn2_b, zbuf, N);

    // ---- sequence features ----
    k_build_x<<<dim3(BT), dim3(192), 0, stream>>>(zbuf, seq, durations, dur_W1, dur_b1, dur_W2, dur_b2, xbuf);

    // ---- input-gate GEMMs ----
    k_transpose_wih<<<dim3(320), dim3(256), 0, stream>>>(Wih_f, Wih_b, WihT_f, WihT_b);
    k_gemm<<<dim3(512/NT, BT/MT), dim3(256), 0, stream>>>(xbuf, WihT_f, b_f, xg_f, BT, 512, 160);
    k_gemm<<<dim3(512/NT, BT/MT), dim3(256), 0, stream>>>(xbuf, WihT_b, b_b, xg_b, BT, 512, 160);

    // ---- BiLSTM recurrence (persistent blocks, dynamic LPT) ----
    k_lstm<<<dim3(256), dim3(1024), 0, stream>>>(xg_f, xg_b, Whh_f, Whh_b, lengths, jobs, counter, lstm_out, T, 2*B);

    // ---- attention ----
    k_attn<<<dim3(B), dim3(256), 0, stream>>>(lstm_out, attn_W, lengths, context, T);

    // ---- final FC: (256 x 256) @ (256 x 100000) + fc_b ----
    k_gemm<<<dim3((N + NT - 1)/NT, B/MT), dim3(256), 0, stream>>>(context, fc_W, fc_b, out, B, N, 256);
}